// Round 11
// baseline (169.566 us; speedup 1.0000x reference)
//
#include <hip/hip_runtime.h>

// DDLG autoencoder, fully fused, batch-tile 4, fp16 packed compute.
//   out[b][o] = sum_f prob[o][f] * op_f(x[b][idx[o][0..7]])
// R1: divide-free Einstein reductions via homomorphisms:
//     ein-product = 2D/(N+D),  D=prod(f), N=prod(2-f)
//     ein-sum     = (N-D)/(N+D), N=prod(1+f), D=prod(1-f)
// R5: 48 KB LDS, 1024-thr blocks, 2 blocks/CU (measured-best residency).
// R8: combined-denominator finale (one rcp pair per h2 over s1*s2; range
//     proof: s1*s2 <= 2.25^8 + 257 ~ 914 < 65504, numerators <= 912).
// R14: chain in explicit VOP3P asm (WIN -5%: hipcc pk lowering is leaky).
// R15: finale in VOP3P asm with op_sel P-broadcast (WIN -2%).
// R16: FAILED -- 36-reg row prefetch spilled to scratch (WRITE 64->74 MB,
//     VGPR pinned at 32). Allocator spill threshold is between 10 and 36
//     held regs.
// R17 (this round): idx-only rolling prefetch -- hold just the NEXT gate's
//     idx+P (10 regs) across the current chain, FENCE-pinned. Hides the
//     ~200-300cy L2 idx/probs head of every gate under the previous gate's
//     pure-asm chain; peak live ~48 VGPR < 64 budget (spill-mode excluded).
//     Plus: consecutive-o ownership -- L0/L2 pair results into one
//     ds_write_b128 (16B stride, conflict-free); L3 owns 4t..4t+3 with
//     float4 output stores (16 dword stores -> 4 dwordx4).
//     Spill tell: WRITE_SIZE must stay 64 MB / FETCH ~37 MB.
//     LDS overlays (fp16 rows of 4 = 8 B, ds_read_b64 gathers):
//       x @ [0,16384) | h0 @ [16384,24576) | h1 @ [0,4096) | h2 @ [16384,24576)

typedef _Float16 h2 __attribute__((ext_vector_type(2)));
typedef _Float16 h4 __attribute__((ext_vector_type(4)));

__device__ __forceinline__ float fastrcp(float x) { return __builtin_amdgcn_rcpf(x); }
__device__ __forceinline__ _Float16 hrcp(_Float16 x) {
#if __has_builtin(__builtin_amdgcn_rcph)
    return __builtin_amdgcn_rcph(x);
#else
    return (_Float16)__builtin_amdgcn_rcpf((float)x);
#endif
}
__device__ __forceinline__ unsigned packh2(float a, float b) {
    h2 v = {(_Float16)a, (_Float16)b};
    return __builtin_bit_cast(unsigned, v);
}
__device__ __forceinline__ h2 ash2(unsigned u) { return __builtin_bit_cast(h2, u); }

#define FENCE() asm volatile("" ::: "memory")

// ---------------- forced VOP3P packed-fp16 ops (2 elems / 1 inst) ----------------
__device__ __forceinline__ unsigned pk_min(unsigned a, unsigned b) {
    unsigned d; asm("v_pk_min_f16 %0, %1, %2" : "=v"(d) : "v"(a), "v"(b)); return d;
}
__device__ __forceinline__ unsigned pk_max(unsigned a, unsigned b) {
    unsigned d; asm("v_pk_max_f16 %0, %1, %2" : "=v"(d) : "v"(a), "v"(b)); return d;
}
__device__ __forceinline__ unsigned pk_mul(unsigned a, unsigned b) {
    unsigned d; asm("v_pk_mul_f16 %0, %1, %2" : "=v"(d) : "v"(a), "v"(b)); return d;
}
__device__ __forceinline__ unsigned pk_add(unsigned a, unsigned b) {
    unsigned d; asm("v_pk_add_f16 %0, %1, %2" : "=v"(d) : "v"(a), "v"(b)); return d;
}
__device__ __forceinline__ unsigned pk_sub(unsigned a, unsigned b) {   // a - b
    unsigned d;
    asm("v_pk_add_f16 %0, %1, %2 neg_lo:[0,1] neg_hi:[0,1]" : "=v"(d) : "v"(a), "v"(b));
    return d;
}
__device__ __forceinline__ unsigned pk_fma(unsigned a, unsigned b, unsigned c) { // a*b+c
    unsigned d;
    asm("v_pk_fma_f16 %0, %1, %2, %3" : "=v"(d) : "v"(a), "v"(b), "v"(c));
    return d;
}
__device__ __forceinline__ unsigned pk_fnma(unsigned a, unsigned b, unsigned c) { // c-a*b
    unsigned d;
    asm("v_pk_fma_f16 %0, %1, %2, %3 neg_lo:[1,0,0] neg_hi:[1,0,0]"
        : "=v"(d) : "v"(a), "v"(b), "v"(c));
    return d;
}
// a * broadcast(b.lo)  -- both result halves read b's LOW half
__device__ __forceinline__ unsigned pk_mul_blo(unsigned a, unsigned b) {
    unsigned d;
    asm("v_pk_mul_f16 %0, %1, %2 op_sel:[0,0] op_sel_hi:[1,0]" : "=v"(d) : "v"(a), "v"(b));
    return d;
}
// a * broadcast(b.hi) + c
__device__ __forceinline__ unsigned pk_fma_bhi(unsigned a, unsigned b, unsigned c) {
    unsigned d;
    asm("v_pk_fma_f16 %0, %1, %2, %3 op_sel:[0,1,0] op_sel_hi:[1,1,1]"
        : "=v"(d) : "v"(a), "v"(b), "v"(c));
    return d;
}

#define PK_ONE 0x3C003C00u   // {1.0h, 1.0h}
#define PK_TWO 0x40004000u   // {2.0h, 2.0h}

// ---------------- prep: fp16 prob table only ----------------
// probsH: [0,2048) L0 | [2048,3072) L1 | [3072,5120) L2 | [5120,9216) L3
__global__ __launch_bounds__(256) void prep_k(const float* __restrict__ w0,
                                              const float* __restrict__ w1,
                                              const float* __restrict__ w2,
                                              const float* __restrict__ w3,
                                              const int* __restrict__ is_train,
                                              h4* __restrict__ probsH) {
    const int g = blockIdx.x * 256 + threadIdx.x;   // grid 36 -> 9216 exact
    const float* w; int o;
    if (g < 2048)      { w = w0; o = g; }
    else if (g < 3072) { w = w1; o = g - 2048; }
    else if (g < 5120) { w = w2; o = g - 3072; }
    else               { w = w3; o = g - 5120; }
    float wv[4];
#pragma unroll
    for (int c = 0; c < 4; ++c) wv[c] = w[(o << 2) + c];
    float p[4];
    if (*is_train) {
        float m = fmaxf(fmaxf(wv[0], wv[1]), fmaxf(wv[2], wv[3]));
        float s = 0.0f;
#pragma unroll
        for (int c = 0; c < 4; ++c) { p[c] = __expf(wv[c] - m); s += p[c]; }
        float inv = fastrcp(s);
#pragma unroll
        for (int c = 0; c < 4; ++c) p[c] *= inv;
    } else {
        int a = 0; float best = wv[0];
#pragma unroll
        for (int c = 1; c < 4; ++c) if (wv[c] > best) { best = wv[c]; a = c; }
#pragma unroll
        for (int c = 0; c < 4; ++c) p[c] = (c == a) ? 1.0f : 0.0f;
    }
    probsH[g] = h4{(_Float16)p[0], (_Float16)p[1], (_Float16)p[2], (_Float16)p[3]};
}

// ---------------- chain state: 6 reductions x 2 packed halves, in uint bits ----
struct Chain { unsigned mn0, mn1, mx0, mx1, De0, De1, Ne0, Ne1, Nc0, Nc1, Dc0, Dc1; };

__device__ __forceinline__ void cinit(Chain& C, uint2 v) {
    C.mn0 = v.x; C.mx0 = v.x; C.De0 = v.x;
    C.Ne0 = pk_sub(PK_TWO, v.x); C.Nc0 = pk_add(PK_ONE, v.x); C.Dc0 = pk_sub(PK_ONE, v.x);
    C.mn1 = v.y; C.mx1 = v.y; C.De1 = v.y;
    C.Ne1 = pk_sub(PK_TWO, v.y); C.Nc1 = pk_add(PK_ONE, v.y); C.Dc1 = pk_sub(PK_ONE, v.y);
}
__device__ __forceinline__ void cstep(Chain& C, uint2 v) {
    C.mn0 = pk_min(C.mn0, v.x);            C.mn1 = pk_min(C.mn1, v.y);
    C.mx0 = pk_max(C.mx0, v.x);            C.mx1 = pk_max(C.mx1, v.y);
    C.De0 = pk_mul(C.De0, v.x);            C.De1 = pk_mul(C.De1, v.y);
    const unsigned w0 = pk_sub(PK_TWO, v.x), w1 = pk_sub(PK_TWO, v.y);
    C.Ne0 = pk_mul(C.Ne0, w0);             C.Ne1 = pk_mul(C.Ne1, w1);
    C.Nc0 = pk_fma(C.Nc0, v.x, C.Nc0);     C.Nc1 = pk_fma(C.Nc1, v.y, C.Nc1);   // *= (1+v)
    C.Dc0 = pk_fnma(C.Dc0, v.x, C.Dc0);    C.Dc1 = pk_fnma(C.Dc1, v.y, C.Dc1);  // *= (1-v)
}

// combined-denominator finale, all-pk with op_sel P broadcast.
__device__ __forceinline__ unsigned finale_half(unsigned mn, unsigned mx,
                                                unsigned De, unsigned Ne,
                                                unsigned Nc, unsigned Dc,
                                                unsigned P01, unsigned P23) {
    const unsigned s1 = pk_add(Ne, De);          // [1, 257]
    const unsigned s2 = pk_add(Nc, Dc);          // [1, 257]
    const unsigned d1 = pk_sub(Nc, Dc);          // [0, 256]
    const unsigned ss = pk_mul(s1, s2);          // <= ~914: fp16-safe
    const h2 ssh = ash2(ss);
    h2 rh = {hrcp(ssh[0]), hrcp(ssh[1])};        // 2x v_rcp_f16 + pack
    const unsigned r  = __builtin_bit_cast(unsigned, rh);
    const unsigned t1 = pk_mul(pk_add(De, De), s2);   // 2*De*s2 <= 514
    const unsigned t2 = pk_mul(d1, s1);               // <= 912
    const unsigned num  = pk_fma_bhi(t2, P23, pk_mul_blo(t1, P23));  // P2*t1+P3*t2
    const unsigned base = pk_fma_bhi(mx, P01, pk_mul_blo(mn, P01));  // P0*mn+P1*mx
    return pk_fma(num, r, base);
}

// ---------------- rolling prefetch state: idx + P only (10 VGPRs) ----------------
struct IP { int4 i0, i1; uint2 P; };

__device__ __forceinline__ IP load_ip(const int4* __restrict__ idx,
                                      const uint2* __restrict__ probs, int o) {
    IP p;
    p.i0 = idx[o * 2];
    p.i1 = idx[o * 2 + 1];
    p.P  = probs[o];
    return p;
}

// gather 8 rows for an IP (8x ds_read_b64)
__device__ __forceinline__ void gath(uint2 A[8], const uint2* __restrict__ rows,
                                     const IP& p) {
    A[0] = rows[p.i0.x]; A[1] = rows[p.i0.y]; A[2] = rows[p.i0.z]; A[3] = rows[p.i0.w];
    A[4] = rows[p.i1.x]; A[5] = rows[p.i1.y]; A[6] = rows[p.i1.z]; A[7] = rows[p.i1.w];
}

// pure-register asm chain + finale
__device__ __forceinline__ uint2 run_gate(const uint2 A[8], uint2 P) {
    Chain C; cinit(C, A[0]);
#pragma unroll
    for (int c = 1; c < 8; ++c) cstep(C, A[c]);
    return uint2{finale_half(C.mn0, C.mx0, C.De0, C.Ne0, C.Nc0, C.Dc0, P.x, P.y),
                 finale_half(C.mn1, C.mx1, C.De1, C.Ne1, C.Nc1, C.Dc1, P.x, P.y)};
}

// ---------------- the fused network ----------------
// grid = 1024 (one block per 4-batch tile), block = 1024, 48 KB, 2 blocks/CU
__global__ __launch_bounds__(1024, 8) void ddlg_fused(const float* __restrict__ x,
                                                      const uint2* __restrict__ probsH,
                                                      const int4* __restrict__ idx0,
                                                      const int4* __restrict__ idx1,
                                                      const int4* __restrict__ idx2,
                                                      const int4* __restrict__ idx3,
                                                      float* __restrict__ out) {
    __shared__ __align__(16) _Float16 lds[24576];   // 48 KB
    const int t  = threadIdx.x;
    const int b0 = blockIdx.x << 2;

    const uint2* xl  = (const uint2*)lds;            // rows [0,4096)
    const uint2* h0v = (const uint2*)(lds + 16384);  // rows [0,2048)
    const uint2* h1v = (const uint2*)lds;            // rows [0,1024) (over dead x)
    const uint2* h2v = (const uint2*)(lds + 16384);  // rows [0,2048) (over dead h0)
    uint4* const hw128 = (uint4*)(lds + 16384);      // paired rows 2t,2t+1
    uint2* const h1w   = (uint2*)lds;

    const uint2* pr0 = probsH;
    const uint2* pr1 = probsH + 2048;
    const uint2* pr2 = probsH + 3072;
    const uint2* pr3 = probsH + 5120;

    // ---- L0's two IPs issue first: L2-latency hidden under staging ----
    IP qa = load_ip(idx0, pr0, 2 * t);
    IP qb = load_ip(idx0, pr0, 2 * t + 1);

    // ---- stage x: thread owns rows j = t + 1024c; 4 coalesced loads -> b64 ----
#pragma unroll
    for (int c = 0; c < 4; ++c) {
        const int j = (c << 10) + t;
        const float v0 = x[(size_t)(b0 + 0) * 4096 + j];
        const float v1 = x[(size_t)(b0 + 1) * 4096 + j];
        const float v2 = x[(size_t)(b0 + 2) * 4096 + j];
        const float v3 = x[(size_t)(b0 + 3) * 4096 + j];
        ((uint2*)lds)[j] = uint2{packh2(v0, v1), packh2(v2, v3)};
    }
    __syncthreads();

    uint2 A[8];

    // ---- L0: 4096 -> 2048, o = 2t, 2t+1; rolling IP prefetch ----
    {
        gath(A, xl, qa);
        IP qc = load_ip(idx1, pr1, t);            // L1 head, in flight during chain
        FENCE();
        uint2 rA = run_gate(A, qa.P);
        gath(A, xl, qb);
        qa = load_ip(idx2, pr2, 2 * t);           // L2.g0
        FENCE();
        uint2 rB = run_gate(A, qb.P);
        hw128[t] = uint4{rA.x, rA.y, rB.x, rB.y}; // rows 2t,2t+1: one b128, 16B stride
        qb = qc;
    }
    __syncthreads();

    // ---- L1: 2048 -> 1024, o = t (IP = qb) ----
    {
        gath(A, h0v, qb);
        IP qc = load_ip(idx2, pr2, 2 * t + 1);    // L2.g1
        FENCE();
        uint2 r = run_gate(A, qb.P);
        h1w[t] = r;
        qb = qc;
    }
    __syncthreads();

    // ---- L2: 1024 -> 2048, o = 2t, 2t+1 (IPs = qa, qb) ----
    {
        gath(A, h1v, qa);
        IP qc = load_ip(idx3, pr3, 4 * t);        // L3.g0
        FENCE();
        uint2 rA = run_gate(A, qa.P);
        gath(A, h1v, qb);
        qa = load_ip(idx3, pr3, 4 * t + 1);       // L3.g1
        FENCE();
        uint2 rB = run_gate(A, qb.P);
        hw128[t] = uint4{rA.x, rA.y, rB.x, rB.y}; // h2 over dead h0
        qb = qc;
    }
    __syncthreads();

    // ---- L3: 2048 -> 4096, o = 4t..4t+3 (IPs roll qb,qa -> new); float4 stores ----
    {
        gath(A, h2v, qb);
        IP qc = load_ip(idx3, pr3, 4 * t + 2);    // L3.g2
        FENCE();
        uint2 r0 = run_gate(A, qb.P);
        gath(A, h2v, qa);
        IP qd = load_ip(idx3, pr3, 4 * t + 3);    // L3.g3
        FENCE();
        uint2 r1 = run_gate(A, qa.P);
        gath(A, h2v, qc);
        FENCE();
        uint2 r2 = run_gate(A, qc.P);
        gath(A, h2v, qd);
        uint2 r3 = run_gate(A, qd.P);

        h2 l0 = ash2(r0.x), h0_ = ash2(r0.y);
        h2 l1 = ash2(r1.x), h1_ = ash2(r1.y);
        h2 l2 = ash2(r2.x), h2_ = ash2(r2.y);
        h2 l3 = ash2(r3.x), h3_ = ash2(r3.y);
        const int j0 = t << 2;
        *(float4*)(out + (size_t)(b0 + 0) * 4096 + j0) =
            make_float4((float)l0[0], (float)l1[0], (float)l2[0], (float)l3[0]);
        *(float4*)(out + (size_t)(b0 + 1) * 4096 + j0) =
            make_float4((float)l0[1], (float)l1[1], (float)l2[1], (float)l3[1]);
        *(float4*)(out + (size_t)(b0 + 2) * 4096 + j0) =
            make_float4((float)h0_[0], (float)h1_[0], (float)h2_[0], (float)h3_[0]);
        *(float4*)(out + (size_t)(b0 + 3) * 4096 + j0) =
            make_float4((float)h0_[1], (float)h1_[1], (float)h2_[1], (float)h3_[1]);
    }
}

extern "C" void kernel_launch(void* const* d_in, const int* in_sizes, int n_in,
                              void* d_out, int out_size, void* d_ws, size_t ws_size,
                              hipStream_t stream) {
    const float* x        = (const float*)d_in[0];
    const float* w0       = (const float*)d_in[1];
    const float* w1       = (const float*)d_in[2];
    const float* w2       = (const float*)d_in[3];
    const float* w3       = (const float*)d_in[4];
    const int4*  idx0     = (const int4*)d_in[5];
    const int4*  idx1     = (const int4*)d_in[6];
    const int4*  idx2     = (const int4*)d_in[7];
    const int4*  idx3     = (const int4*)d_in[8];
    const int*   is_train = (const int*)d_in[9];
    float*       out      = (float*)d_out;

    // ws: probsH 9216*8B = 72 KB @0
    h4* probsH = (h4*)d_ws;

    prep_k<<<36, 256, 0, stream>>>(w0, w1, w2, w3, is_train, probsH);
    ddlg_fused<<<1024, 1024, 0, stream>>>(x, (const uint2*)probsH,
                                          idx0, idx1, idx2, idx3, out);
}